// Round 4
// baseline (1059.348 us; speedup 1.0000x reference)
//
#include <hip/hip_runtime.h>

#define IS2f 0.70710678118654752440f

// workspace offsets in floats
#define WS_Z   0ul          // 1024 * 2048
#define WS_G   2097152ul    // 1024 * 1024
#define WS_H   3145728ul    // 1024 * 1024
#define WS_SU  4194304ul    // 131072: [ci][b][j][c][l]
#define WS_VV  4325376ul    // 524288: [ci][b][j][l][n]
#define WS_B   4849664ul    // optional: 1024 * 8192 (32 MB)

// single-wave compiler memory barrier: LDS ops within one wave execute in
// issue order in HW; we only need to stop compiler reordering/caching.
#define WSYNC() asm volatile("" ::: "memory")

__device__ __forceinline__ float frcp(float v){ return __builtin_amdgcn_rcpf(v); }
__device__ __forceinline__ float frsq(float v){ return __builtin_amdgcn_rsqf(v); }
__device__ __forceinline__ float fsq (float v){ return __builtin_amdgcn_sqrtf(v); }
__device__ __forceinline__ float readlane_f(float v, int sl){
  return __uint_as_float(__builtin_amdgcn_readlane(__float_as_uint(v), sl));
}

__device__ __forceinline__ void decode_pid(int pid, int& ci, int& b, int& l, int& L){
  if (pid < 512)      { ci = 0; b = pid >> 7; l = pid & 127; L = 128; }
  else if (pid < 768) { int q = pid - 512; ci = 1; b = q >> 6; l = q & 63; L = 64; }
  else                { int q = pid - 768; ci = 2; b = q >> 6; l = q & 63; L = 64; }
}
__device__ __forceinline__ int su_base(int ci){ return ci==0 ? 0 : (ci==1 ? 65536 : 98304); }
__device__ __forceinline__ int vv_base(int ci){ return ci==0 ? 0 : (ci==1 ? 262144 : 393216); }

// ---------------------------------------------------------------------------
// Kernel 1: per problem (ci,b,l): M (64x256) -> Z=M*p (64x32), G=Z^T Z,
// B=Z^T M (LDS; optionally stored), H=B B^T.  Store Z,G,H(,B) to ws.
// ---------------------------------------------------------------------------
__global__ __launch_bounds__(256) void k_fact(const float* __restrict__ x,
                                              const float* __restrict__ p,
                                              float* __restrict__ ws, int storeB){
  __shared__ __align__(16) float Ms[64*256];
  __shared__ __align__(16) float Zs[64*32];
  __shared__ float Bt[256*33];               // B transposed: Bt[n][k], pad 33
  __shared__ __align__(16) float Ps[256*32];

  int pid = blockIdx.x, tid = threadIdx.x;
  int ci,b,l,L; decode_pid(pid,ci,b,l,L);

  // stage p (256x32)
  {
    const float4* p4 = (const float4*)p;
    float4* Ps4 = (float4*)Ps;
    #pragma unroll
    for (int e=0;e<8;++e) Ps4[tid + 256*e] = p4[tid + 256*e];
  }
  // load M with on-the-fly Haar combine.  x f4 layout: ((b*256+t)*64+c)*64+g
  const float4* x4 = (const float4*)x;
  float4* Ms4 = (float4*)Ms;
  if (ci == 0){
    size_t base = ((size_t)(b*256 + 2*l) * 64) * 64;
    #pragma unroll
    for (int e=0;e<16;++e){
      int f = tid + 256*e;
      float4 A = x4[base + f];
      float4 Bv = x4[base + 4096 + f];
      float4 m;
      m.x=(A.x-Bv.x)*IS2f; m.y=(A.y-Bv.y)*IS2f; m.z=(A.z-Bv.z)*IS2f; m.w=(A.w-Bv.w)*IS2f;
      Ms4[f] = m;
    }
  } else {
    float sg = (ci==1) ? -0.5f : 0.5f;
    size_t base = ((size_t)(b*256 + 4*l) * 64) * 64;
    #pragma unroll
    for (int e=0;e<16;++e){
      int f = tid + 256*e;
      float4 A = x4[base + f];
      float4 B1 = x4[base + 4096 + f];
      float4 C1 = x4[base + 8192 + f];
      float4 D1 = x4[base + 12288 + f];
      float4 m;
      m.x=(A.x+B1.x)*0.5f + (C1.x+D1.x)*sg;
      m.y=(A.y+B1.y)*0.5f + (C1.y+D1.y)*sg;
      m.z=(A.z+B1.z)*0.5f + (C1.z+D1.z)*sg;
      m.w=(A.w+B1.w)*0.5f + (C1.w+D1.w)*sg;
      Ms4[f] = m;
    }
  }
  __syncthreads();

  // Z[c][k] = sum_n M[c][n] * p[n][k]
  {
    int k = tid & 31, c0 = tid >> 5;
    float acc[8] = {0,0,0,0,0,0,0,0};
    #pragma unroll 4
    for (int n4=0;n4<64;++n4){
      float p0 = Ps[(4*n4+0)*32 + k];
      float p1 = Ps[(4*n4+1)*32 + k];
      float p2 = Ps[(4*n4+2)*32 + k];
      float p3 = Ps[(4*n4+3)*32 + k];
      #pragma unroll
      for (int i=0;i<8;++i){
        float4 m = Ms4[(c0*8+i)*64 + n4];
        acc[i] += m.x*p0 + m.y*p1 + m.z*p2 + m.w*p3;
      }
    }
    #pragma unroll
    for (int i=0;i<8;++i){
      int c = c0*8 + i;
      Zs[c*32+k] = acc[i];
      ws[WS_Z + (size_t)pid*2048 + c*32 + k] = acc[i];
    }
  }
  __syncthreads();

  // G = Z^T Z (32x32)
  #pragma unroll
  for (int e=0;e<4;++e){
    int jk = tid + 256*e; int j = jk>>5, kk = jk&31;
    float a = 0.f;
    #pragma unroll 4
    for (int c=0;c<64;++c) a += Zs[c*32+j]*Zs[c*32+kk];
    ws[WS_G + (size_t)pid*1024 + jk] = a;
  }
  // B[k][n] = sum_c Z[c][k] M[c][n]  -> Bt[n][k]
  {
    int n4 = tid & 63, kg = tid >> 6;
    #pragma unroll
    for (int kq=0;kq<8;++kq){
      int kk = kg*8 + kq;
      float ax=0.f, ay=0.f, az=0.f, aw=0.f;
      #pragma unroll 4
      for (int c=0;c<64;++c){
        float zv = Zs[c*32+kk];
        float4 mv = Ms4[c*64 + n4];
        ax += zv*mv.x; ay += zv*mv.y; az += zv*mv.z; aw += zv*mv.w;
      }
      Bt[(n4*4+0)*33 + kk] = ax;
      Bt[(n4*4+1)*33 + kk] = ay;
      Bt[(n4*4+2)*33 + kk] = az;
      Bt[(n4*4+3)*33 + kk] = aw;
    }
  }
  __syncthreads();

  if (storeB){
    int n = tid;
    #pragma unroll 4
    for (int k=0;k<32;++k)
      ws[WS_B + (size_t)pid*8192 + k*256 + n] = Bt[n*33 + k];
  }

  // H = B B^T (32x32)
  #pragma unroll
  for (int e=0;e<4;++e){
    int jk = tid + 256*e; int j = jk>>5, kk = jk&31;
    float a = 0.f;
    #pragma unroll 4
    for (int n=0;n<256;++n) a += Bt[n*33+j]*Bt[n*33+kk];
    ws[WS_H + (size_t)pid*1024 + jk] = a;
  }
}

// ---------------------------------------------------------------------------
// Kernel 2: per problem, 1 wave, wave-synchronous.  Jacobi phases are
// strict load-batch -> compute-batch (no shfl, partner values read directly;
// lanes j and j+32 read identical addresses -> LDS broadcast).
// ---------------------------------------------------------------------------
#define NSWEEP 5

__global__ __launch_bounds__(64) void k_solve(const float* __restrict__ x,
                                              float* __restrict__ ws, int useB){
  __shared__ float Gs[32*33];
  __shared__ float Hs[32*33];
  __shared__ float Vsh[32*33];
  __shared__ float ggs[2][32];
  __shared__ float uss[2][64];

  int pid = blockIdx.x, lane = threadIdx.x;
  int ci,b,l,L; decode_pid(pid,ci,b,l,L);
  int jlane = lane & 31, hlf = lane >> 5;

  #pragma unroll
  for (int e=0;e<16;++e){
    int idx = lane + 64*e; int i = idx>>5, j = idx&31;
    Gs[i*33+j]  = ws[WS_G + (size_t)pid*1024 + idx];
    Hs[i*33+j]  = ws[WS_H + (size_t)pid*1024 + idx];
    Vsh[i*33+j] = (i==j) ? 1.f : 0.f;
  }
  WSYNC();

  // ---- Cholesky (upper): G = R^T R, batched right-looking trailing updates.
  for (int k=0;k<32;++k){
    float gkk = Gs[k*33+k];
    float sD  = frsq(gkk);
    if (lane == k) Gs[k*33+k] = gkk * sD;           // = sqrt(gkk)
    if (lane > k && lane < 32) Gs[k*33+lane] *= sD;
    WSYNC();
    float gkj = Gs[k*33+jlane];
    float av[16], bv[16];
    #pragma unroll
    for (int e=0;e<16;++e){
      int i = k+1+hlf+2*e; int ii = (i<32)? i : 31;
      av[e] = Gs[ii*33+jlane];
      bv[e] = Gs[k*33+ii];
    }
    WSYNC();
    #pragma unroll
    for (int e=0;e<16;++e){
      int i = k+1+hlf+2*e;
      if (i < 32) Gs[i*33+jlane] = av[e] - bv[e]*gkj;
    }
    WSYNC();
  }
  float rdgr = frcp(Gs[jlane*33+jlane]);   // 1/R[jlane][jlane], both halves

  // ---- X = R^-T H  (solve R^T X = H), batched
  for (int i=0;i<32;++i){
    float rdi = __shfl(rdgr, i);
    if (lane < 32) Hs[i*33+lane] *= rdi;
    WSYNC();
    float hij = Hs[i*33+jlane];
    float av[16], bv[16];
    #pragma unroll
    for (int e=0;e<16;++e){
      int m = i+1+hlf+2*e; int mm = (m<32)? m : 31;
      av[e] = Hs[mm*33+jlane];
      bv[e] = Gs[i*33+mm];
    }
    WSYNC();
    #pragma unroll
    for (int e=0;e<16;++e){
      int m = i+1+hlf+2*e;
      if (m < 32) Hs[m*33+jlane] = av[e] - bv[e]*hij;
    }
    WSYNC();
  }
  // ---- W = X R^-1  (solve W R = X), batched over columns
  for (int j=0;j<32;++j){
    float rdj = __shfl(rdgr, j);
    if (lane < 32) Hs[lane*33+j] *= rdj;
    WSYNC();
    float hij = Hs[jlane*33+j];
    float av[16], bv[16];
    #pragma unroll
    for (int e=0;e<16;++e){
      int m = j+1+hlf+2*e; int mm = (m<32)? m : 31;
      av[e] = Hs[jlane*33+mm];
      bv[e] = Gs[j*33+mm];
    }
    WSYNC();
    #pragma unroll
    for (int e=0;e<16;++e){
      int m = j+1+hlf+2*e;
      if (m < 32) Hs[jlane*33+m] = av[e] - bv[e]*hij;
    }
    WSYNC();
  }

  // ---- parallel cyclic Jacobi: pure load-batch then compute-batch phases
  for (int sw=0; sw<NSWEEP; ++sw){
    for (int r=0; r<31; ++r){
      // params: lanes 0..15 own pair m; lanes 16+ duplicate (harmless)
      int m = lane & 15;
      int pp = (m==0) ? r  : (r+m)%31;
      int qq = (m==0) ? 31 : (r+31-m)%31;
      float app = Hs[pp*33+pp];
      float aqq = Hs[qq*33+qq];
      float apq = Hs[pp*33+qq];
      float tau = (aqq - app) * frcp(2.f*apq);
      float tt  = ((tau>=0.f)?1.f:-1.f) * frcp(fabsf(tau) + fsq(fmaf(tau,tau,1.f)));
      float cc  = frsq(fmaf(tt,tt,1.f));
      float ss  = tt*cc;
      bool ok = fabsf(apq) > 1e-28f;
      float cpar = ok ? cc : 1.f;
      float spar = ok ? ss : 0.f;
      WSYNC();
      // ---- row phase: load batch (32 reads, lanes j/j+32 broadcast)
      {
        float hp[16], hq[16];
        #pragma unroll
        for (int e=0;e<16;++e){
          int sp = (e==0) ? r  : (r+e)%31;
          int sq = (e==0) ? 31 : (r+31-e)%31;
          hp[e] = Hs[sp*33+jlane];
          hq[e] = Hs[sq*33+jlane];
        }
        WSYNC();
        #pragma unroll
        for (int e=0;e<16;++e){
          int sp = (e==0) ? r  : (r+e)%31;
          int sq = (e==0) ? 31 : (r+31-e)%31;
          float ce = readlane_f(cpar, e);
          float se = readlane_f(spar, e);
          float nv = hlf ? fmaf(se, hp[e], ce*hq[e])
                         : fmaf(-se, hq[e], ce*hp[e]);
          Hs[(hlf ? sq : sp)*33 + jlane] = nv;
        }
      }
      WSYNC();
      // ---- col phase: load batch (64 reads: H and V), then compute+store
      {
        float hp[16], hq[16], vp[16], vq[16];
        #pragma unroll
        for (int e=0;e<16;++e){
          int sp = (e==0) ? r  : (r+e)%31;
          int sq = (e==0) ? 31 : (r+31-e)%31;
          hp[e] = Hs[jlane*33+sp];  hq[e] = Hs[jlane*33+sq];
          vp[e] = Vsh[jlane*33+sp]; vq[e] = Vsh[jlane*33+sq];
        }
        WSYNC();
        #pragma unroll
        for (int e=0;e<16;++e){
          int sp = (e==0) ? r  : (r+e)%31;
          int sq = (e==0) ? 31 : (r+31-e)%31;
          float ce = readlane_f(cpar, e);
          float se = readlane_f(spar, e);
          int col = hlf ? sq : sp;
          float nh = hlf ? fmaf(se, hp[e], ce*hq[e]) : fmaf(-se, hq[e], ce*hp[e]);
          float nv = hlf ? fmaf(se, vp[e], ce*vq[e]) : fmaf(-se, vq[e], ce*vp[e]);
          Hs[jlane*33+col]  = nh;
          Vsh[jlane*33+col] = nv;
        }
      }
      WSYNC();
    }
  }

  // ---- top-2 eigenvalues: lane-parallel reduce
  float dv = (lane < 32) ? Hs[jlane*33+jlane] : -3e38f;
  float m1 = dv;
  #pragma unroll
  for (int off=1; off<64; off<<=1) m1 = fmaxf(m1, __shfl_xor(m1, off));
  unsigned long long bm = __ballot(dv == m1);
  int i0 = __ffsll((unsigned long long)bm) - 1;
  float dv2 = (lane == i0) ? -3e38f : dv;
  float m2 = dv2;
  #pragma unroll
  for (int off=1; off<64; off<<=1) m2 = fmaxf(m2, __shfl_xor(m2, off));
  unsigned long long bm2 = __ballot(dv2 == m2);
  int i1 = __ffsll((unsigned long long)bm2) - 1;

  float lam = hlf ? m2 : m1;
  int   ti  = hlf ? i1 : i0;
  float sj  = fsq(fmaxf(lam, 0.f)); sj = fmaxf(sj, 1e-12f);
  float s0 = readlane_f(sj, 0);
  float s1 = readlane_f(sj, 32);

  // ---- back-solve R g = w, register-resident, fully unrolled
  {
    float rr = Vsh[jlane*33 + ti];
    float Greg[32];
    #pragma unroll
    for (int i=0;i<32;++i) Greg[i] = Gs[jlane*33+i];
    #pragma unroll
    for (int i=31;i>=0;--i){
      float ri = __shfl(rr,  hlf*32 + i);
      float di = __shfl(rdgr, i);
      float g  = ri * di;
      if (jlane == i) ggs[hlf][i] = g;
      if (jlane < i)  rr -= Greg[i]*g;
    }
  }
  WSYNC();

  // ---- u = Z g (lane = c)
  {
    const float4* Z4 = (const float4*)(ws + WS_Z + (size_t)pid*2048);
    float u0 = 0.f, u1 = 0.f;
    #pragma unroll
    for (int k4=0;k4<8;++k4){
      float4 z = Z4[lane*8 + k4];
      u0 += z.x*ggs[0][k4*4+0] + z.y*ggs[0][k4*4+1] + z.z*ggs[0][k4*4+2] + z.w*ggs[0][k4*4+3];
      u1 += z.x*ggs[1][k4*4+0] + z.y*ggs[1][k4*4+1] + z.z*ggs[1][k4*4+2] + z.w*ggs[1][k4*4+3];
    }
    uss[0][lane] = u0; uss[1][lane] = u1;
    ws[WS_SU + su_base(ci) + ((size_t)(b*2+0)*64 + lane)*L + l] = s0*u0;
    ws[WS_SU + su_base(ci) + ((size_t)(b*2+1)*64 + lane)*L + l] = s1*u1;
  }
  WSYNC();

  float i0s = frcp(s0), i1s = frcp(s1);
  size_t vb0 = WS_VV + vv_base(ci) + ((size_t)(b*2+0)*L + l)*256 + lane*4;
  size_t vb1 = WS_VV + vv_base(ci) + ((size_t)(b*2+1)*L + l)*256 + lane*4;

  if (useB){
    // vh_j = (g_j^T B) / s_j
    const float4* B4 = (const float4*)(ws + WS_B + (size_t)pid*8192);
    float a0x=0,a0y=0,a0z=0,a0w=0, a1x=0,a1y=0,a1z=0,a1w=0;
    #pragma unroll 8
    for (int k=0;k<32;++k){
      float4 bv = B4[(size_t)k*64 + lane];
      float g0 = ggs[0][k], g1 = ggs[1][k];
      a0x += g0*bv.x; a0y += g0*bv.y; a0z += g0*bv.z; a0w += g0*bv.w;
      a1x += g1*bv.x; a1y += g1*bv.y; a1z += g1*bv.z; a1w += g1*bv.w;
    }
    float4 r0; r0.x=a0x*i0s; r0.y=a0y*i0s; r0.z=a0z*i0s; r0.w=a0w*i0s;
    float4 r1; r1.x=a1x*i1s; r1.y=a1y*i1s; r1.z=a1z*i1s; r1.w=a1w*i1s;
    *(float4*)(ws + vb0) = r0;
    *(float4*)(ws + vb1) = r1;
  } else {
    // vh_j = u_j^T M / s_j, streaming x
    float a0x=0,a0y=0,a0z=0,a0w=0, a1x=0,a1y=0,a1z=0,a1w=0;
    const float4* x4 = (const float4*)x;
    if (ci == 0){
      size_t base = ((size_t)(b*256 + 2*l) * 64) * 64;
      #pragma unroll 2
      for (int c=0;c<64;++c){
        float4 A  = x4[base + c*64 + lane];
        float4 Bv = x4[base + 4096 + c*64 + lane];
        float mx=(A.x-Bv.x)*IS2f, my=(A.y-Bv.y)*IS2f, mz=(A.z-Bv.z)*IS2f, mw=(A.w-Bv.w)*IS2f;
        float uc0 = uss[0][c], uc1 = uss[1][c];
        a0x += uc0*mx; a0y += uc0*my; a0z += uc0*mz; a0w += uc0*mw;
        a1x += uc1*mx; a1y += uc1*my; a1z += uc1*mz; a1w += uc1*mw;
      }
    } else {
      float sg = (ci==1) ? -0.5f : 0.5f;
      size_t base = ((size_t)(b*256 + 4*l) * 64) * 64;
      #pragma unroll 2
      for (int c=0;c<64;++c){
        float4 A  = x4[base + c*64 + lane];
        float4 B1 = x4[base + 4096 + c*64 + lane];
        float4 C1 = x4[base + 8192 + c*64 + lane];
        float4 D1 = x4[base + 12288 + c*64 + lane];
        float mx=(A.x+B1.x)*0.5f + (C1.x+D1.x)*sg;
        float my=(A.y+B1.y)*0.5f + (C1.y+D1.y)*sg;
        float mz=(A.z+B1.z)*0.5f + (C1.z+D1.z)*sg;
        float mw=(A.w+B1.w)*0.5f + (C1.w+D1.w)*sg;
        float uc0 = uss[0][c], uc1 = uss[1][c];
        a0x += uc0*mx; a0y += uc0*my; a0z += uc0*mz; a0w += uc0*mw;
        a1x += uc1*mx; a1y += uc1*my; a1z += uc1*mz; a1w += uc1*mw;
      }
    }
    ws[vb0+0]=a0x*i0s; ws[vb0+1]=a0y*i0s; ws[vb0+2]=a0z*i0s; ws[vb0+3]=a0w*i0s;
    ws[vb1+0]=a1x*i1s; ws[vb1+1]=a1y*i1s; ws[vb1+2]=a1z*i1s; ws[vb1+3]=a1w*i1s;
  }
}

// ---------------------------------------------------------------------------
// Kernel 3: writer (unchanged).
// ---------------------------------------------------------------------------
__global__ __launch_bounds__(256) void k_out(const float* __restrict__ x,
                                             const float* __restrict__ ws,
                                             float* __restrict__ out){
  __shared__ float d1[128*33];
  __shared__ float d2[64*33];
  __shared__ float a2s[64*33];
  __shared__ float Vs[2*128*33];   // also aliased as a1 during Haar
  __shared__ float Us[512];

  int nt = blockIdx.x, c = blockIdx.y, b = blockIdx.z;
  int n0 = nt * 32, tid = threadIdx.x;
  float* a1 = Vs;

  const float4* x4 = (const float4*)x;
  #pragma unroll
  for (int e=0;e<4;++e){
    int f = tid + 256*e; int l1 = f>>3, d4 = f&7;
    size_t r = ((size_t)(b*256 + 2*l1)*64 + c)*64 + (n0>>2) + d4;
    float4 A = x4[r], Bv = x4[r + 4096];
    int o = l1*33 + 4*d4;
    d1[o+0]=(A.x-Bv.x)*IS2f; d1[o+1]=(A.y-Bv.y)*IS2f; d1[o+2]=(A.z-Bv.z)*IS2f; d1[o+3]=(A.w-Bv.w)*IS2f;
    a1[o+0]=(A.x+Bv.x)*IS2f; a1[o+1]=(A.y+Bv.y)*IS2f; a1[o+2]=(A.z+Bv.z)*IS2f; a1[o+3]=(A.w+Bv.w)*IS2f;
  }
  __syncthreads();
  #pragma unroll
  for (int e=0;e<2;++e){
    int f = tid + 256*e; int l2 = f>>3, d4 = f&7;
    #pragma unroll
    for (int j=0;j<4;++j){
      int dn = 4*d4 + j;
      float aa = a1[(2*l2)*33 + dn], bb = a1[(2*l2+1)*33 + dn];
      d2[l2*33+dn]  = (aa-bb)*IS2f;
      a2s[l2*33+dn] = (aa+bb)*IS2f;
    }
  }
  #pragma unroll
  for (int e=0;e<2;++e){
    int idx = tid + 256*e;
    int j, l, L, so;
    if (idx < 256)      { j=idx>>7;        l=idx&127; L=128; so=0; }
    else if (idx < 384) { j=(idx-256)>>6;  l=idx&63;  L=64;  so=65536; }
    else                { j=(idx-384)>>6;  l=idx&63;  L=64;  so=98304; }
    Us[idx] = ws[WS_SU + so + ((size_t)(b*2+j)*64 + c)*L + l];
  }
  __syncthreads();

  for (int cc=0; cc<3; ++cc){
    int L   = (cc==0) ? 128 : 64;
    int pad = 256 - L;
    int sb  = cc*3;
    int uo  = (cc==0) ? 0 : (cc==1) ? 256 : 384;
    const float* cf = (cc==0) ? d1 : (cc==1) ? d2 : a2s;

    int iters = (2*L*32) >> 8;
    for (int e=0;e<iters;++e){
      int idx = tid + 256*e;
      int j = (idx >= L*32) ? 1 : 0;
      int rem = idx - j*L*32;
      int ll = rem >> 5, dn = rem & 31;
      Vs[j*4224 + ll*33 + dn] =
        ws[WS_VV + vv_base(cc) + ((size_t)(b*2+j)*L + ll)*256 + n0 + dn];
    }
    __syncthreads();

    int l = tid - pad;
    bool inr = (l >= 0);
    size_t obase = (size_t)sb*16777216 + (size_t)b*4194304 + (size_t)c*65536
                 + (size_t)n0*256 + tid;
    #pragma unroll 4
    for (int dn=0; dn<32; ++dn){
      float v0 = 0.f, v1 = 0.f, rv = 0.f;
      if (inr){
        float q0 = Us[uo + l]     * Vs[l*33 + dn];
        float q1 = Us[uo + L + l] * Vs[4224 + l*33 + dn];
        v0 = q0; v1 = q1;
        rv = cf[l*33 + dn] - q0 - q1;
      }
      out[obase + dn*256]            = v0;
      out[obase + dn*256 + 16777216] = v1;
      out[obase + dn*256 + 33554432] = rv;
    }
    __syncthreads();
  }
}

// ---------------------------------------------------------------------------
extern "C" void kernel_launch(void* const* d_in, const int* in_sizes, int n_in,
                              void* d_out, int out_size, void* d_ws, size_t ws_size,
                              hipStream_t stream) {
  const float* x = (const float*)d_in[0];   // (4,256,64,256) f32
  const float* p = (const float*)d_in[1];   // (256,32) f32
  float* out = (float*)d_out;               // (9,4,64,256,256) f32
  float* ws  = (float*)d_ws;

  int useB = (ws_size >= (size_t)(WS_B + 1024ull*8192ull) * 4ull) ? 1 : 0;

  k_fact <<<1024, 256, 0, stream>>>(x, p, ws, useB);
  k_solve<<<1024,  64, 0, stream>>>(x, ws, useB);
  k_out  <<<dim3(8,64,4), 256, 0, stream>>>(x, ws, out);
}

// Round 5
// 638.223 us; speedup vs baseline: 1.6598x; 1.6598x over previous
//
#include <hip/hip_runtime.h>

#define IS2f 0.70710678118654752440f

// workspace offsets in floats
#define WS_Z   0ul          // 1024 * 2048
#define WS_G   2097152ul    // 1024 * 1024
#define WS_H   3145728ul    // 1024 * 1024
#define WS_SU  4194304ul    // 131072: [ci][b][j][c][l]
#define WS_VV  4325376ul    // 524288: [ci][b][j][l][n]
#define WS_B   4849664ul    // optional: 1024 * 8192 (32 MB)

// single-wave compiler memory barrier
#define WSYNC() asm volatile("" ::: "memory")

__device__ __forceinline__ float frcp(float v){ return __builtin_amdgcn_rcpf(v); }
__device__ __forceinline__ float frsq(float v){ return __builtin_amdgcn_rsqf(v); }
__device__ __forceinline__ float fsq (float v){ return __builtin_amdgcn_sqrtf(v); }
__device__ __forceinline__ float readlane_f(float v, int sl){
  return __uint_as_float(__builtin_amdgcn_readlane(__float_as_uint(v), sl));
}

__device__ __forceinline__ void decode_pid(int pid, int& ci, int& b, int& l, int& L){
  if (pid < 512)      { ci = 0; b = pid >> 7; l = pid & 127; L = 128; }
  else if (pid < 768) { int q = pid - 512; ci = 1; b = q >> 6; l = q & 63; L = 64; }
  else                { int q = pid - 768; ci = 2; b = q >> 6; l = q & 63; L = 64; }
}
__device__ __forceinline__ int su_base(int ci){ return ci==0 ? 0 : (ci==1 ? 65536 : 98304); }
__device__ __forceinline__ int vv_base(int ci){ return ci==0 ? 0 : (ci==1 ? 262144 : 393216); }
// tournament pair (round r, slot m), n=32
__device__ __forceinline__ int tpp(int r, int m){ return (m==0) ? r  : (r+m)%31; }
__device__ __forceinline__ int tqq(int r, int m){ return (m==0) ? 31 : (r+31-m)%31; }

// ---------------------------------------------------------------------------
// Kernel 1: per problem (ci,b,l): M (64x256) -> Z=M*p (64x32), G=Z^T Z,
// B=Z^T M (LDS; optionally stored), H=B B^T.  Store Z,G,H(,B) to ws.
// ---------------------------------------------------------------------------
__global__ __launch_bounds__(256) void k_fact(const float* __restrict__ x,
                                              const float* __restrict__ p,
                                              float* __restrict__ ws, int storeB){
  __shared__ __align__(16) float Ms[64*256];
  __shared__ __align__(16) float Zs[64*32];
  __shared__ float Bt[256*33];
  __shared__ __align__(16) float Ps[256*32];

  int pid = blockIdx.x, tid = threadIdx.x;
  int ci,b,l,L; decode_pid(pid,ci,b,l,L);

  {
    const float4* p4 = (const float4*)p;
    float4* Ps4 = (float4*)Ps;
    #pragma unroll
    for (int e=0;e<8;++e) Ps4[tid + 256*e] = p4[tid + 256*e];
  }
  const float4* x4 = (const float4*)x;
  float4* Ms4 = (float4*)Ms;
  if (ci == 0){
    size_t base = ((size_t)(b*256 + 2*l) * 64) * 64;
    #pragma unroll
    for (int e=0;e<16;++e){
      int f = tid + 256*e;
      float4 A = x4[base + f];
      float4 Bv = x4[base + 4096 + f];
      float4 m;
      m.x=(A.x-Bv.x)*IS2f; m.y=(A.y-Bv.y)*IS2f; m.z=(A.z-Bv.z)*IS2f; m.w=(A.w-Bv.w)*IS2f;
      Ms4[f] = m;
    }
  } else {
    float sg = (ci==1) ? -0.5f : 0.5f;
    size_t base = ((size_t)(b*256 + 4*l) * 64) * 64;
    #pragma unroll
    for (int e=0;e<16;++e){
      int f = tid + 256*e;
      float4 A = x4[base + f];
      float4 B1 = x4[base + 4096 + f];
      float4 C1 = x4[base + 8192 + f];
      float4 D1 = x4[base + 12288 + f];
      float4 m;
      m.x=(A.x+B1.x)*0.5f + (C1.x+D1.x)*sg;
      m.y=(A.y+B1.y)*0.5f + (C1.y+D1.y)*sg;
      m.z=(A.z+B1.z)*0.5f + (C1.z+D1.z)*sg;
      m.w=(A.w+B1.w)*0.5f + (C1.w+D1.w)*sg;
      Ms4[f] = m;
    }
  }
  __syncthreads();

  {
    int k = tid & 31, c0 = tid >> 5;
    float acc[8] = {0,0,0,0,0,0,0,0};
    #pragma unroll 4
    for (int n4=0;n4<64;++n4){
      float p0 = Ps[(4*n4+0)*32 + k];
      float p1 = Ps[(4*n4+1)*32 + k];
      float p2 = Ps[(4*n4+2)*32 + k];
      float p3 = Ps[(4*n4+3)*32 + k];
      #pragma unroll
      for (int i=0;i<8;++i){
        float4 m = Ms4[(c0*8+i)*64 + n4];
        acc[i] += m.x*p0 + m.y*p1 + m.z*p2 + m.w*p3;
      }
    }
    #pragma unroll
    for (int i=0;i<8;++i){
      int c = c0*8 + i;
      Zs[c*32+k] = acc[i];
      ws[WS_Z + (size_t)pid*2048 + c*32 + k] = acc[i];
    }
  }
  __syncthreads();

  #pragma unroll
  for (int e=0;e<4;++e){
    int jk = tid + 256*e; int j = jk>>5, kk = jk&31;
    float a = 0.f;
    #pragma unroll 4
    for (int c=0;c<64;++c) a += Zs[c*32+j]*Zs[c*32+kk];
    ws[WS_G + (size_t)pid*1024 + jk] = a;
  }
  {
    int n4 = tid & 63, kg = tid >> 6;
    #pragma unroll
    for (int kq=0;kq<8;++kq){
      int kk = kg*8 + kq;
      float ax=0.f, ay=0.f, az=0.f, aw=0.f;
      #pragma unroll 4
      for (int c=0;c<64;++c){
        float zv = Zs[c*32+kk];
        float4 mv = Ms4[c*64 + n4];
        ax += zv*mv.x; ay += zv*mv.y; az += zv*mv.z; aw += zv*mv.w;
      }
      Bt[(n4*4+0)*33 + kk] = ax;
      Bt[(n4*4+1)*33 + kk] = ay;
      Bt[(n4*4+2)*33 + kk] = az;
      Bt[(n4*4+3)*33 + kk] = aw;
    }
  }
  __syncthreads();

  if (storeB){
    int n = tid;
    #pragma unroll 4
    for (int k=0;k<32;++k)
      ws[WS_B + (size_t)pid*8192 + k*256 + n] = Bt[n*33 + k];
  }

  #pragma unroll
  for (int e=0;e<4;++e){
    int jk = tid + 256*e; int j = jk>>5, kk = jk&31;
    float a = 0.f;
    #pragma unroll 4
    for (int n=0;n<256;++n) a += Bt[n*33+j]*Bt[n*33+kk];
    ws[WS_H + (size_t)pid*1024 + jk] = a;
  }
}

// ---------------------------------------------------------------------------
// Kernel 2: per problem, 1 wave, wave-synchronous.  Jacobi = single-pass
// 2x2 congruence per (m1,m2) worker + round skipping.
// ---------------------------------------------------------------------------
#define NSWEEP 5

__global__ __launch_bounds__(64) void k_solve(const float* __restrict__ x,
                                              float* __restrict__ ws, int useB){
  __shared__ float Gs[32*33];
  __shared__ float Hs[32*33];
  __shared__ float Vsh[32*33];
  __shared__ float cA[16], sA[16];
  __shared__ float ggs[2][32];
  __shared__ float uss[2][64];

  int pid = blockIdx.x, lane = threadIdx.x;
  int ci,b,l,L; decode_pid(pid,ci,b,l,L);
  int jlane = lane & 31, hlf = lane >> 5;

  #pragma unroll
  for (int e=0;e<16;++e){
    int idx = lane + 64*e; int i = idx>>5, j = idx&31;
    Gs[i*33+j]  = ws[WS_G + (size_t)pid*1024 + idx];
    Hs[i*33+j]  = ws[WS_H + (size_t)pid*1024 + idx];
    Vsh[i*33+j] = (i==j) ? 1.f : 0.f;
  }
  WSYNC();

  // ---- Cholesky (upper): G = R^T R, batched right-looking
  for (int k=0;k<32;++k){
    float gkk = Gs[k*33+k];
    float sD  = frsq(gkk);
    if (lane == k) Gs[k*33+k] = gkk * sD;
    if (lane > k && lane < 32) Gs[k*33+lane] *= sD;
    WSYNC();
    float gkj = Gs[k*33+jlane];
    float av[16], bv[16];
    #pragma unroll
    for (int e=0;e<16;++e){
      int i = k+1+hlf+2*e; int ii = (i<32)? i : 31;
      av[e] = Gs[ii*33+jlane];
      bv[e] = Gs[k*33+ii];
    }
    WSYNC();
    #pragma unroll
    for (int e=0;e<16;++e){
      int i = k+1+hlf+2*e;
      if (i < 32) Gs[i*33+jlane] = av[e] - bv[e]*gkj;
    }
    WSYNC();
  }
  float rdgr = frcp(Gs[jlane*33+jlane]);

  // ---- X = R^-T H
  for (int i=0;i<32;++i){
    float rdi = __shfl(rdgr, i);
    if (lane < 32) Hs[i*33+lane] *= rdi;
    WSYNC();
    float hij = Hs[i*33+jlane];
    float av[16], bv[16];
    #pragma unroll
    for (int e=0;e<16;++e){
      int m = i+1+hlf+2*e; int mm = (m<32)? m : 31;
      av[e] = Hs[mm*33+jlane];
      bv[e] = Gs[i*33+mm];
    }
    WSYNC();
    #pragma unroll
    for (int e=0;e<16;++e){
      int m = i+1+hlf+2*e;
      if (m < 32) Hs[m*33+jlane] = av[e] - bv[e]*hij;
    }
    WSYNC();
  }
  // ---- W = X R^-1
  for (int j=0;j<32;++j){
    float rdj = __shfl(rdgr, j);
    if (lane < 32) Hs[lane*33+j] *= rdj;
    WSYNC();
    float hij = Hs[jlane*33+j];
    float av[16], bv[16];
    #pragma unroll
    for (int e=0;e<16;++e){
      int m = j+1+hlf+2*e; int mm = (m<32)? m : 31;
      av[e] = Hs[jlane*33+mm];
      bv[e] = Gs[j*33+mm];
    }
    WSYNC();
    #pragma unroll
    for (int e=0;e<16;++e){
      int m = j+1+hlf+2*e;
      if (m < 32) Hs[jlane*33+m] = av[e] - bv[e]*hij;
    }
    WSYNC();
  }

  // skip threshold from diag magnitude
  float dmx = (lane < 32) ? fabsf(Hs[jlane*33+jlane]) : 0.f;
  #pragma unroll
  for (int off=1; off<64; off<<=1) dmx = fmaxf(dmx, __shfl_xor(dmx, off));
  float thr = dmx * 3e-6f;

  // ---- Jacobi: single-pass 2x2 congruence, round skip
  int m2 = lane >> 2;     // this lane's right-rotation pair (0..15)
  int lm = lane & 3;      // base for left pairs {lm, lm+4, lm+8, lm+12}
  for (int sw=0; sw<NSWEEP; ++sw){
    for (int r=0; r<31; ++r){
      // rotation params: redundant across 4 lane-groups
      int m = lane & 15;
      int pm = tpp(r,m), qm = tqq(r,m);
      float app = Hs[pm*33+pm];
      float aqq = Hs[qm*33+qm];
      float apq = Hs[pm*33+qm];
      if (!__ballot(fabsf(apq) > thr)) continue;   // converged round
      float tau = (aqq - app) * frcp(2.f*apq);
      float tt  = ((tau>=0.f)?1.f:-1.f) * frcp(fabsf(tau) + fsq(fmaf(tau,tau,1.f)));
      float cc  = frsq(fmaf(tt,tt,1.f));
      float ss  = tt*cc;
      bool ok = fabsf(apq) > 1e-28f;
      if (lane < 16){ cA[lane] = ok?cc:1.f; sA[lane] = ok?ss:0.f; }
      WSYNC();

      // ---- H: 4 workers (m1 = lm+4e, m2 fixed): read 2x2, rotate LR, write
      int p2 = tpp(r,m2), q2 = tqq(r,m2);
      float c2 = cA[m2], s2 = sA[m2];
      float a_[4], b_[4], c_[4], d_[4], c1v[4], s1v[4];
      int p1v[4], q1v[4];
      #pragma unroll
      for (int e=0;e<4;++e){
        int m1 = lm + 4*e;
        int p1 = tpp(r,m1), q1 = tqq(r,m1);
        p1v[e]=p1; q1v[e]=q1;
        c1v[e]=cA[m1]; s1v[e]=sA[m1];
        a_[e] = Hs[p1*33+p2]; b_[e] = Hs[p1*33+q2];
        c_[e] = Hs[q1*33+p2]; d_[e] = Hs[q1*33+q2];
      }
      // V: 8 workers (rows i = lm+4e, cols p2,q2)
      float vp[8], vq[8];
      #pragma unroll
      for (int e=0;e<8;++e){
        int i = lm + 4*e;
        vp[e] = Vsh[i*33+p2];
        vq[e] = Vsh[i*33+q2];
      }
      WSYNC();
      #pragma unroll
      for (int e=0;e<4;++e){
        float c1 = c1v[e], s1 = s1v[e];
        // left rotation (rows p1,q1)
        float a1 = c1*a_[e] - s1*c_[e];
        float b1 = c1*b_[e] - s1*d_[e];
        float c1r= s1*a_[e] + c1*c_[e];
        float d1 = s1*b_[e] + c1*d_[e];
        // right rotation (cols p2,q2)
        Hs[p1v[e]*33+p2] = c2*a1 - s2*b1;
        Hs[p1v[e]*33+q2] = s2*a1 + c2*b1;
        Hs[q1v[e]*33+p2] = c2*c1r - s2*d1;
        Hs[q1v[e]*33+q2] = s2*c1r + c2*d1;
      }
      #pragma unroll
      for (int e=0;e<8;++e){
        int i = lm + 4*e;
        Vsh[i*33+p2] = c2*vp[e] - s2*vq[e];
        Vsh[i*33+q2] = s2*vp[e] + c2*vq[e];
      }
      WSYNC();
    }
  }

  // ---- top-2 eigenvalues
  float dv = (lane < 32) ? Hs[jlane*33+jlane] : -3e38f;
  float m1r = dv;
  #pragma unroll
  for (int off=1; off<64; off<<=1) m1r = fmaxf(m1r, __shfl_xor(m1r, off));
  unsigned long long bm = __ballot(dv == m1r);
  int i0 = __ffsll((unsigned long long)bm) - 1;
  float dv2 = (lane == i0) ? -3e38f : dv;
  float m2r = dv2;
  #pragma unroll
  for (int off=1; off<64; off<<=1) m2r = fmaxf(m2r, __shfl_xor(m2r, off));
  unsigned long long bm2 = __ballot(dv2 == m2r);
  int i1 = __ffsll((unsigned long long)bm2) - 1;

  float lam = hlf ? m2r : m1r;
  int   ti  = hlf ? i1 : i0;
  float sj  = fsq(fmaxf(lam, 0.f)); sj = fmaxf(sj, 1e-12f);
  float s0 = readlane_f(sj, 0);
  float s1 = readlane_f(sj, 32);

  // ---- back-solve R g = w, register-resident
  {
    float rr = Vsh[jlane*33 + ti];
    float Greg[32];
    #pragma unroll
    for (int i=0;i<32;++i) Greg[i] = Gs[jlane*33+i];
    #pragma unroll
    for (int i=31;i>=0;--i){
      float ri = __shfl(rr,  hlf*32 + i);
      float di = __shfl(rdgr, i);
      float g  = ri * di;
      if (jlane == i) ggs[hlf][i] = g;
      if (jlane < i)  rr -= Greg[i]*g;
    }
  }
  WSYNC();

  // ---- u = Z g
  {
    const float4* Z4 = (const float4*)(ws + WS_Z + (size_t)pid*2048);
    float u0 = 0.f, u1 = 0.f;
    #pragma unroll
    for (int k4=0;k4<8;++k4){
      float4 z = Z4[lane*8 + k4];
      u0 += z.x*ggs[0][k4*4+0] + z.y*ggs[0][k4*4+1] + z.z*ggs[0][k4*4+2] + z.w*ggs[0][k4*4+3];
      u1 += z.x*ggs[1][k4*4+0] + z.y*ggs[1][k4*4+1] + z.z*ggs[1][k4*4+2] + z.w*ggs[1][k4*4+3];
    }
    uss[0][lane] = u0; uss[1][lane] = u1;
    ws[WS_SU + su_base(ci) + ((size_t)(b*2+0)*64 + lane)*L + l] = s0*u0;
    ws[WS_SU + su_base(ci) + ((size_t)(b*2+1)*64 + lane)*L + l] = s1*u1;
  }
  WSYNC();

  float i0s = frcp(s0), i1s = frcp(s1);
  size_t vb0 = WS_VV + vv_base(ci) + ((size_t)(b*2+0)*L + l)*256 + lane*4;
  size_t vb1 = WS_VV + vv_base(ci) + ((size_t)(b*2+1)*L + l)*256 + lane*4;

  if (useB){
    const float4* B4 = (const float4*)(ws + WS_B + (size_t)pid*8192);
    float a0x=0,a0y=0,a0z=0,a0w=0, a1x=0,a1y=0,a1z=0,a1w=0;
    #pragma unroll 8
    for (int k=0;k<32;++k){
      float4 bv = B4[(size_t)k*64 + lane];
      float g0 = ggs[0][k], g1 = ggs[1][k];
      a0x += g0*bv.x; a0y += g0*bv.y; a0z += g0*bv.z; a0w += g0*bv.w;
      a1x += g1*bv.x; a1y += g1*bv.y; a1z += g1*bv.z; a1w += g1*bv.w;
    }
    float4 r0; r0.x=a0x*i0s; r0.y=a0y*i0s; r0.z=a0z*i0s; r0.w=a0w*i0s;
    float4 r1; r1.x=a1x*i1s; r1.y=a1y*i1s; r1.z=a1z*i1s; r1.w=a1w*i1s;
    *(float4*)(ws + vb0) = r0;
    *(float4*)(ws + vb1) = r1;
  } else {
    float a0x=0,a0y=0,a0z=0,a0w=0, a1x=0,a1y=0,a1z=0,a1w=0;
    const float4* x4 = (const float4*)x;
    if (ci == 0){
      size_t base = ((size_t)(b*256 + 2*l) * 64) * 64;
      #pragma unroll 2
      for (int c=0;c<64;++c){
        float4 A  = x4[base + c*64 + lane];
        float4 Bv = x4[base + 4096 + c*64 + lane];
        float mx=(A.x-Bv.x)*IS2f, my=(A.y-Bv.y)*IS2f, mz=(A.z-Bv.z)*IS2f, mw=(A.w-Bv.w)*IS2f;
        float uc0 = uss[0][c], uc1 = uss[1][c];
        a0x += uc0*mx; a0y += uc0*my; a0z += uc0*mz; a0w += uc0*mw;
        a1x += uc1*mx; a1y += uc1*my; a1z += uc1*mz; a1w += uc1*mw;
      }
    } else {
      float sg = (ci==1) ? -0.5f : 0.5f;
      size_t base = ((size_t)(b*256 + 4*l) * 64) * 64;
      #pragma unroll 2
      for (int c=0;c<64;++c){
        float4 A  = x4[base + c*64 + lane];
        float4 B1 = x4[base + 4096 + c*64 + lane];
        float4 C1 = x4[base + 8192 + c*64 + lane];
        float4 D1 = x4[base + 12288 + c*64 + lane];
        float mx=(A.x+B1.x)*0.5f + (C1.x+D1.x)*sg;
        float my=(A.y+B1.y)*0.5f + (C1.y+D1.y)*sg;
        float mz=(A.z+B1.z)*0.5f + (C1.z+D1.z)*sg;
        float mw=(A.w+B1.w)*0.5f + (C1.w+D1.w)*sg;
        float uc0 = uss[0][c], uc1 = uss[1][c];
        a0x += uc0*mx; a0y += uc0*my; a0z += uc0*mz; a0w += uc0*mw;
        a1x += uc1*mx; a1y += uc1*my; a1z += uc1*mz; a1w += uc1*mw;
      }
    }
    ws[vb0+0]=a0x*i0s; ws[vb0+1]=a0y*i0s; ws[vb0+2]=a0z*i0s; ws[vb0+3]=a0w*i0s;
    ws[vb1+0]=a1x*i1s; ws[vb1+1]=a1y*i1s; ws[vb1+2]=a1z*i1s; ws[vb1+3]=a1w*i1s;
  }
}

// ---------------------------------------------------------------------------
// Kernel 3: writer (unchanged).
// ---------------------------------------------------------------------------
__global__ __launch_bounds__(256) void k_out(const float* __restrict__ x,
                                             const float* __restrict__ ws,
                                             float* __restrict__ out){
  __shared__ float d1[128*33];
  __shared__ float d2[64*33];
  __shared__ float a2s[64*33];
  __shared__ float Vs[2*128*33];
  __shared__ float Us[512];

  int nt = blockIdx.x, c = blockIdx.y, b = blockIdx.z;
  int n0 = nt * 32, tid = threadIdx.x;
  float* a1 = Vs;

  const float4* x4 = (const float4*)x;
  #pragma unroll
  for (int e=0;e<4;++e){
    int f = tid + 256*e; int l1 = f>>3, d4 = f&7;
    size_t r = ((size_t)(b*256 + 2*l1)*64 + c)*64 + (n0>>2) + d4;
    float4 A = x4[r], Bv = x4[r + 4096];
    int o = l1*33 + 4*d4;
    d1[o+0]=(A.x-Bv.x)*IS2f; d1[o+1]=(A.y-Bv.y)*IS2f; d1[o+2]=(A.z-Bv.z)*IS2f; d1[o+3]=(A.w-Bv.w)*IS2f;
    a1[o+0]=(A.x+Bv.x)*IS2f; a1[o+1]=(A.y+Bv.y)*IS2f; a1[o+2]=(A.z+Bv.z)*IS2f; a1[o+3]=(A.w+Bv.w)*IS2f;
  }
  __syncthreads();
  #pragma unroll
  for (int e=0;e<2;++e){
    int f = tid + 256*e; int l2 = f>>3, d4 = f&7;
    #pragma unroll
    for (int j=0;j<4;++j){
      int dn = 4*d4 + j;
      float aa = a1[(2*l2)*33 + dn], bb = a1[(2*l2+1)*33 + dn];
      d2[l2*33+dn]  = (aa-bb)*IS2f;
      a2s[l2*33+dn] = (aa+bb)*IS2f;
    }
  }
  #pragma unroll
  for (int e=0;e<2;++e){
    int idx = tid + 256*e;
    int j, l, L, so;
    if (idx < 256)      { j=idx>>7;        l=idx&127; L=128; so=0; }
    else if (idx < 384) { j=(idx-256)>>6;  l=idx&63;  L=64;  so=65536; }
    else                { j=(idx-384)>>6;  l=idx&63;  L=64;  so=98304; }
    Us[idx] = ws[WS_SU + so + ((size_t)(b*2+j)*64 + c)*L + l];
  }
  __syncthreads();

  for (int cc=0; cc<3; ++cc){
    int L   = (cc==0) ? 128 : 64;
    int pad = 256 - L;
    int sb  = cc*3;
    int uo  = (cc==0) ? 0 : (cc==1) ? 256 : 384;
    const float* cf = (cc==0) ? d1 : (cc==1) ? d2 : a2s;

    int iters = (2*L*32) >> 8;
    for (int e=0;e<iters;++e){
      int idx = tid + 256*e;
      int j = (idx >= L*32) ? 1 : 0;
      int rem = idx - j*L*32;
      int ll = rem >> 5, dn = rem & 31;
      Vs[j*4224 + ll*33 + dn] =
        ws[WS_VV + vv_base(cc) + ((size_t)(b*2+j)*L + ll)*256 + n0 + dn];
    }
    __syncthreads();

    int l = tid - pad;
    bool inr = (l >= 0);
    size_t obase = (size_t)sb*16777216 + (size_t)b*4194304 + (size_t)c*65536
                 + (size_t)n0*256 + tid;
    #pragma unroll 4
    for (int dn=0; dn<32; ++dn){
      float v0 = 0.f, v1 = 0.f, rv = 0.f;
      if (inr){
        float q0 = Us[uo + l]     * Vs[l*33 + dn];
        float q1 = Us[uo + L + l] * Vs[4224 + l*33 + dn];
        v0 = q0; v1 = q1;
        rv = cf[l*33 + dn] - q0 - q1;
      }
      out[obase + dn*256]            = v0;
      out[obase + dn*256 + 16777216] = v1;
      out[obase + dn*256 + 33554432] = rv;
    }
    __syncthreads();
  }
}

// ---------------------------------------------------------------------------
extern "C" void kernel_launch(void* const* d_in, const int* in_sizes, int n_in,
                              void* d_out, int out_size, void* d_ws, size_t ws_size,
                              hipStream_t stream) {
  const float* x = (const float*)d_in[0];
  const float* p = (const float*)d_in[1];
  float* out = (float*)d_out;
  float* ws  = (float*)d_ws;

  int useB = (ws_size >= (size_t)(WS_B + 1024ull*8192ull) * 4ull) ? 1 : 0;

  k_fact <<<1024, 256, 0, stream>>>(x, p, ws, useB);
  k_solve<<<1024,  64, 0, stream>>>(x, ws, useB);
  k_out  <<<dim3(8,64,4), 256, 0, stream>>>(x, ws, out);
}

// Round 6
// 564.752 us; speedup vs baseline: 1.8758x; 1.1301x over previous
//
#include <hip/hip_runtime.h>

#define IS2f 0.70710678118654752440f

// workspace offsets in floats
#define WS_Z   0ul          // 1024 * 2048
#define WS_G   2097152ul    // 1024 * 1024
#define WS_H   3145728ul    // 1024 * 1024
#define WS_SU  4194304ul    // 131072: [ci][b][j][c][l]
#define WS_VV  4325376ul    // 524288: [ci][b][j][l][n]
#define WS_B   4849664ul    // optional: 1024 * 8192 (32 MB)

// single-wave compiler memory barrier
#define WSYNC() asm volatile("" ::: "memory")

__device__ __forceinline__ float frcp(float v){ return __builtin_amdgcn_rcpf(v); }
__device__ __forceinline__ float frsq(float v){ return __builtin_amdgcn_rsqf(v); }
__device__ __forceinline__ float fsq (float v){ return __builtin_amdgcn_sqrtf(v); }
__device__ __forceinline__ float readlane_f(float v, int sl){
  return __uint_as_float(__builtin_amdgcn_readlane(__float_as_uint(v), sl));
}

__device__ __forceinline__ void decode_pid(int pid, int& ci, int& b, int& l, int& L){
  if (pid < 512)      { ci = 0; b = pid >> 7; l = pid & 127; L = 128; }
  else if (pid < 768) { int q = pid - 512; ci = 1; b = q >> 6; l = q & 63; L = 64; }
  else                { int q = pid - 768; ci = 2; b = q >> 6; l = q & 63; L = 64; }
}
__device__ __forceinline__ int su_base(int ci){ return ci==0 ? 0 : (ci==1 ? 65536 : 98304); }
__device__ __forceinline__ int vv_base(int ci){ return ci==0 ? 0 : (ci==1 ? 262144 : 393216); }
// tournament pair (round r, slot m), n=32
__device__ __forceinline__ int tpp(int r, int m){ return (m==0) ? r  : (r+m)%31; }
__device__ __forceinline__ int tqq(int r, int m){ return (m==0) ? 31 : (r+31-m)%31; }

// ---------------------------------------------------------------------------
// Kernel 1: unchanged from R5.
// ---------------------------------------------------------------------------
__global__ __launch_bounds__(256) void k_fact(const float* __restrict__ x,
                                              const float* __restrict__ p,
                                              float* __restrict__ ws, int storeB){
  __shared__ __align__(16) float Ms[64*256];
  __shared__ __align__(16) float Zs[64*32];
  __shared__ float Bt[256*33];
  __shared__ __align__(16) float Ps[256*32];

  int pid = blockIdx.x, tid = threadIdx.x;
  int ci,b,l,L; decode_pid(pid,ci,b,l,L);

  {
    const float4* p4 = (const float4*)p;
    float4* Ps4 = (float4*)Ps;
    #pragma unroll
    for (int e=0;e<8;++e) Ps4[tid + 256*e] = p4[tid + 256*e];
  }
  const float4* x4 = (const float4*)x;
  float4* Ms4 = (float4*)Ms;
  if (ci == 0){
    size_t base = ((size_t)(b*256 + 2*l) * 64) * 64;
    #pragma unroll
    for (int e=0;e<16;++e){
      int f = tid + 256*e;
      float4 A = x4[base + f];
      float4 Bv = x4[base + 4096 + f];
      float4 m;
      m.x=(A.x-Bv.x)*IS2f; m.y=(A.y-Bv.y)*IS2f; m.z=(A.z-Bv.z)*IS2f; m.w=(A.w-Bv.w)*IS2f;
      Ms4[f] = m;
    }
  } else {
    float sg = (ci==1) ? -0.5f : 0.5f;
    size_t base = ((size_t)(b*256 + 4*l) * 64) * 64;
    #pragma unroll
    for (int e=0;e<16;++e){
      int f = tid + 256*e;
      float4 A = x4[base + f];
      float4 B1 = x4[base + 4096 + f];
      float4 C1 = x4[base + 8192 + f];
      float4 D1 = x4[base + 12288 + f];
      float4 m;
      m.x=(A.x+B1.x)*0.5f + (C1.x+D1.x)*sg;
      m.y=(A.y+B1.y)*0.5f + (C1.y+D1.y)*sg;
      m.z=(A.z+B1.z)*0.5f + (C1.z+D1.z)*sg;
      m.w=(A.w+B1.w)*0.5f + (C1.w+D1.w)*sg;
      Ms4[f] = m;
    }
  }
  __syncthreads();

  {
    int k = tid & 31, c0 = tid >> 5;
    float acc[8] = {0,0,0,0,0,0,0,0};
    #pragma unroll 4
    for (int n4=0;n4<64;++n4){
      float p0 = Ps[(4*n4+0)*32 + k];
      float p1 = Ps[(4*n4+1)*32 + k];
      float p2 = Ps[(4*n4+2)*32 + k];
      float p3 = Ps[(4*n4+3)*32 + k];
      #pragma unroll
      for (int i=0;i<8;++i){
        float4 m = Ms4[(c0*8+i)*64 + n4];
        acc[i] += m.x*p0 + m.y*p1 + m.z*p2 + m.w*p3;
      }
    }
    #pragma unroll
    for (int i=0;i<8;++i){
      int c = c0*8 + i;
      Zs[c*32+k] = acc[i];
      ws[WS_Z + (size_t)pid*2048 + c*32 + k] = acc[i];
    }
  }
  __syncthreads();

  #pragma unroll
  for (int e=0;e<4;++e){
    int jk = tid + 256*e; int j = jk>>5, kk = jk&31;
    float a = 0.f;
    #pragma unroll 4
    for (int c=0;c<64;++c) a += Zs[c*32+j]*Zs[c*32+kk];
    ws[WS_G + (size_t)pid*1024 + jk] = a;
  }
  {
    int n4 = tid & 63, kg = tid >> 6;
    #pragma unroll
    for (int kq=0;kq<8;++kq){
      int kk = kg*8 + kq;
      float ax=0.f, ay=0.f, az=0.f, aw=0.f;
      #pragma unroll 4
      for (int c=0;c<64;++c){
        float zv = Zs[c*32+kk];
        float4 mv = Ms4[c*64 + n4];
        ax += zv*mv.x; ay += zv*mv.y; az += zv*mv.z; aw += zv*mv.w;
      }
      Bt[(n4*4+0)*33 + kk] = ax;
      Bt[(n4*4+1)*33 + kk] = ay;
      Bt[(n4*4+2)*33 + kk] = az;
      Bt[(n4*4+3)*33 + kk] = aw;
    }
  }
  __syncthreads();

  if (storeB){
    int n = tid;
    #pragma unroll 4
    for (int k=0;k<32;++k)
      ws[WS_B + (size_t)pid*8192 + k*256 + n] = Bt[n*33 + k];
  }

  #pragma unroll
  for (int e=0;e<4;++e){
    int jk = tid + 256*e; int j = jk>>5, kk = jk&31;
    float a = 0.f;
    #pragma unroll 4
    for (int n=0;n<256;++n) a += Bt[n*33+j]*Bt[n*33+kk];
    ws[WS_H + (size_t)pid*1024 + jk] = a;
  }
}

// ---------------------------------------------------------------------------
// Kernel 2: 2 waves per problem.  wave0 = params+H (+whole epilogue),
// wave1 = V-updates.  Cholesky/tri-solves: deferred-scaling right-looking,
// trailing rows split over 4 half-waves, 1 barrier per step.
// ---------------------------------------------------------------------------
#define NSWEEP 5

__global__ __launch_bounds__(128) void k_solve(const float* __restrict__ x,
                                               float* __restrict__ ws, int useB){
  __shared__ float Gs[32*33];
  __shared__ float Hs[32*33];
  __shared__ float Vsh[32*33];
  __shared__ float cA[16], sA[16];
  __shared__ float ggs[2][32];
  __shared__ float uss[2][64];

  int pid = blockIdx.x, tid = threadIdx.x;
  int wave = tid >> 6;
  int lane = tid & 63;
  int jlane = tid & 31;
  int wv4  = tid >> 5;          // 0..3
  int hlf  = (tid >> 5) & 1;
  int ci,b,l,L; decode_pid(pid,ci,b,l,L);

  #pragma unroll
  for (int e=0;e<8;++e){
    int idx = tid + 128*e; int i = idx>>5, j = idx&31;
    Gs[i*33+j]  = ws[WS_G + (size_t)pid*1024 + idx];
    Hs[i*33+j]  = ws[WS_H + (size_t)pid*1024 + idx];
    Vsh[i*33+j] = (i==j) ? 1.f : 0.f;
  }
  __syncthreads();

  // ---- Cholesky, right-looking rank-1 (deferred scaling):
  //      A[i][j] -= A[k][i]*A[k][j]/A[k][k]
  for (int k=0;k<32;++k){
    float gkk  = Gs[k*33+k];
    float ginv = frcp(gkk);
    float gkj  = Gs[k*33+jlane];
    float av[8], bv[8];
    #pragma unroll
    for (int e=0;e<8;++e){
      int i = k+1+wv4+4*e; int ii = (i<32)? i : 31;
      av[e] = Gs[ii*33+jlane];
      bv[e] = Gs[k*33+ii];
    }
    WSYNC();
    #pragma unroll
    for (int e=0;e<8;++e){
      int i = k+1+wv4+4*e;
      if (i < 32) Gs[i*33+jlane] = av[e] - bv[e]*gkj*ginv;
    }
    __syncthreads();
  }
  // scale rows -> R (diag becomes sqrt(d))
  {
    float sv[8];
    #pragma unroll
    for (int e=0;e<8;++e){
      int i = wv4+4*e;
      float d = Gs[i*33+i];
      sv[e] = Gs[i*33+jlane] * frsq(d);
    }
    WSYNC();
    #pragma unroll
    for (int e=0;e<8;++e){
      int i = wv4+4*e;
      Gs[i*33+jlane] = sv[e];
    }
  }
  __syncthreads();

  // ---- X = R^-T H  (forward subst, deferred scaling)
  for (int i=0;i<32;++i){
    float rinv = frcp(Gs[i*33+i]);
    float hs   = Hs[i*33+jlane] * rinv;
    float av[8], bv[8];
    #pragma unroll
    for (int e=0;e<8;++e){
      int m = i+1+wv4+4*e; int mm = (m<32)? m : 31;
      av[e] = Hs[mm*33+jlane];
      bv[e] = Gs[i*33+mm];
    }
    WSYNC();
    #pragma unroll
    for (int e=0;e<8;++e){
      int m = i+1+wv4+4*e;
      if (m < 32) Hs[m*33+jlane] = av[e] - bv[e]*hs;
    }
    __syncthreads();
  }
  {
    float sv[8];
    #pragma unroll
    for (int e=0;e<8;++e){
      int m = wv4+4*e;
      sv[e] = Hs[m*33+jlane] * frcp(Gs[m*33+m]);
    }
    WSYNC();
    #pragma unroll
    for (int e=0;e<8;++e){
      int m = wv4+4*e;
      Hs[m*33+jlane] = sv[e];
    }
  }
  __syncthreads();

  // ---- W = X R^-1  (column subst, deferred scaling)
  for (int j=0;j<32;++j){
    float rinv = frcp(Gs[j*33+j]);
    float hs   = Hs[jlane*33+j] * rinv;
    float av[8], bv[8];
    #pragma unroll
    for (int e=0;e<8;++e){
      int m = j+1+wv4+4*e; int mm = (m<32)? m : 31;
      av[e] = Hs[jlane*33+mm];
      bv[e] = Gs[j*33+mm];
    }
    WSYNC();
    #pragma unroll
    for (int e=0;e<8;++e){
      int m = j+1+wv4+4*e;
      if (m < 32) Hs[jlane*33+m] = av[e] - bv[e]*hs;
    }
    __syncthreads();
  }
  {
    float sv[8];
    #pragma unroll
    for (int e=0;e<8;++e){
      int m = wv4+4*e;
      sv[e] = Hs[jlane*33+m] * frcp(Gs[m*33+m]);
    }
    WSYNC();
    #pragma unroll
    for (int e=0;e<8;++e){
      int m = wv4+4*e;
      Hs[jlane*33+m] = sv[e];
    }
  }
  __syncthreads();

  // skip threshold (identical in both waves)
  float dmx = (lane < 32) ? fabsf(Hs[jlane*33+jlane]) : 0.f;
  #pragma unroll
  for (int off=1; off<64; off<<=1) dmx = fmaxf(dmx, __shfl_xor(dmx, off));
  float thr = dmx * 3e-6f;

  // ---- Jacobi: wave0 = params + H tiles; wave1 = V columns
  for (int sw=0; sw<NSWEEP; ++sw){
    for (int r=0; r<31; ++r){
      if (wave == 0){
        int m = lane & 15;
        int pm = tpp(r,m), qm = tqq(r,m);
        float app = Hs[pm*33+pm];
        float aqq = Hs[qm*33+qm];
        float apq = Hs[pm*33+qm];
        if (!__ballot(fabsf(apq) > thr)) continue;
        float tau = (aqq - app) * frcp(2.f*apq);
        float tt  = ((tau>=0.f)?1.f:-1.f) * frcp(fabsf(tau) + fsq(fmaf(tau,tau,1.f)));
        float cc  = frsq(fmaf(tt,tt,1.f));
        float ss  = tt*cc;
        bool ok = fabsf(apq) > 1e-28f;
        if (lane < 16){ cA[lane] = ok?cc:1.f; sA[lane] = ok?ss:0.f; }
        WSYNC();

        int m2 = lane >> 2, lm = lane & 3;
        int p2 = tpp(r,m2), q2 = tqq(r,m2);
        float c2 = cA[m2], s2 = sA[m2];
        float a_[4], b_[4], c_[4], d_[4], c1v[4], s1v[4];
        int p1v[4], q1v[4];
        #pragma unroll
        for (int e=0;e<4;++e){
          int m1 = lm + 4*e;
          int p1 = tpp(r,m1), q1 = tqq(r,m1);
          p1v[e]=p1; q1v[e]=q1;
          c1v[e]=cA[m1]; s1v[e]=sA[m1];
          a_[e] = Hs[p1*33+p2]; b_[e] = Hs[p1*33+q2];
          c_[e] = Hs[q1*33+p2]; d_[e] = Hs[q1*33+q2];
        }
        WSYNC();
        #pragma unroll
        for (int e=0;e<4;++e){
          float c1 = c1v[e], s1 = s1v[e];
          float a1 = c1*a_[e] - s1*c_[e];
          float b1 = c1*b_[e] - s1*d_[e];
          float c1r= s1*a_[e] + c1*c_[e];
          float d1 = s1*b_[e] + c1*d_[e];
          Hs[p1v[e]*33+p2] = c2*a1 - s2*b1;
          Hs[p1v[e]*33+q2] = s2*a1 + c2*b1;
          Hs[q1v[e]*33+p2] = c2*c1r - s2*d1;
          Hs[q1v[e]*33+q2] = s2*c1r + c2*d1;
        }
      } else {
        int m2 = lane >> 2, lm = lane & 3;
        int p2 = tpp(r,m2), q2 = tqq(r,m2);
        float app = Hs[p2*33+p2];
        float aqq = Hs[q2*33+q2];
        float apq = Hs[p2*33+q2];
        if (!__ballot(fabsf(apq) > thr)) continue;
        float tau = (aqq - app) * frcp(2.f*apq);
        float tt  = ((tau>=0.f)?1.f:-1.f) * frcp(fabsf(tau) + fsq(fmaf(tau,tau,1.f)));
        float cc  = frsq(fmaf(tt,tt,1.f));
        float ss  = tt*cc;
        bool ok = fabsf(apq) > 1e-28f;
        float c2 = ok?cc:1.f, s2 = ok?ss:0.f;

        float vp[8], vq[8];
        #pragma unroll
        for (int e=0;e<8;++e){
          int i = lm + 4*e;
          vp[e] = Vsh[i*33+p2];
          vq[e] = Vsh[i*33+q2];
        }
        WSYNC();
        #pragma unroll
        for (int e=0;e<8;++e){
          int i = lm + 4*e;
          Vsh[i*33+p2] = c2*vp[e] - s2*vq[e];
          Vsh[i*33+q2] = s2*vp[e] + c2*vq[e];
        }
      }
      __syncthreads();
    }
  }
  __syncthreads();
  if (wave == 1) return;

  // ================== epilogue: wave0 only ==================
  float rdgr = frcp(Gs[jlane*33+jlane]);

  float dv = (lane < 32) ? Hs[jlane*33+jlane] : -3e38f;
  float m1r = dv;
  #pragma unroll
  for (int off=1; off<64; off<<=1) m1r = fmaxf(m1r, __shfl_xor(m1r, off));
  unsigned long long bm = __ballot(dv == m1r);
  int i0 = __ffsll((unsigned long long)bm) - 1;
  float dv2 = (lane == i0) ? -3e38f : dv;
  float m2r = dv2;
  #pragma unroll
  for (int off=1; off<64; off<<=1) m2r = fmaxf(m2r, __shfl_xor(m2r, off));
  unsigned long long bm2 = __ballot(dv2 == m2r);
  int i1 = __ffsll((unsigned long long)bm2) - 1;

  float lam = hlf ? m2r : m1r;
  int   ti  = hlf ? i1 : i0;
  float sj  = fsq(fmaxf(lam, 0.f)); sj = fmaxf(sj, 1e-12f);
  float s0 = readlane_f(sj, 0);
  float s1 = readlane_f(sj, 32);

  // back-solve R g = w
  {
    float rr = Vsh[jlane*33 + ti];
    float Greg[32];
    #pragma unroll
    for (int i=0;i<32;++i) Greg[i] = Gs[jlane*33+i];
    #pragma unroll
    for (int i=31;i>=0;--i){
      float ri = __shfl(rr,  hlf*32 + i);
      float di = __shfl(rdgr, i);
      float g  = ri * di;
      if (jlane == i) ggs[hlf][i] = g;
      if (jlane < i)  rr -= Greg[i]*g;
    }
  }
  WSYNC();

  // u = Z g
  {
    const float4* Z4 = (const float4*)(ws + WS_Z + (size_t)pid*2048);
    float u0 = 0.f, u1 = 0.f;
    #pragma unroll
    for (int k4=0;k4<8;++k4){
      float4 z = Z4[lane*8 + k4];
      u0 += z.x*ggs[0][k4*4+0] + z.y*ggs[0][k4*4+1] + z.z*ggs[0][k4*4+2] + z.w*ggs[0][k4*4+3];
      u1 += z.x*ggs[1][k4*4+0] + z.y*ggs[1][k4*4+1] + z.z*ggs[1][k4*4+2] + z.w*ggs[1][k4*4+3];
    }
    uss[0][lane] = u0; uss[1][lane] = u1;
    ws[WS_SU + su_base(ci) + ((size_t)(b*2+0)*64 + lane)*L + l] = s0*u0;
    ws[WS_SU + su_base(ci) + ((size_t)(b*2+1)*64 + lane)*L + l] = s1*u1;
  }
  WSYNC();

  float i0s = frcp(s0), i1s = frcp(s1);
  size_t vb0 = WS_VV + vv_base(ci) + ((size_t)(b*2+0)*L + l)*256 + lane*4;
  size_t vb1 = WS_VV + vv_base(ci) + ((size_t)(b*2+1)*L + l)*256 + lane*4;

  if (useB){
    const float4* B4 = (const float4*)(ws + WS_B + (size_t)pid*8192);
    float a0x=0,a0y=0,a0z=0,a0w=0, a1x=0,a1y=0,a1z=0,a1w=0;
    #pragma unroll 8
    for (int k=0;k<32;++k){
      float4 bv = B4[(size_t)k*64 + lane];
      float g0 = ggs[0][k], g1 = ggs[1][k];
      a0x += g0*bv.x; a0y += g0*bv.y; a0z += g0*bv.z; a0w += g0*bv.w;
      a1x += g1*bv.x; a1y += g1*bv.y; a1z += g1*bv.z; a1w += g1*bv.w;
    }
    float4 r0; r0.x=a0x*i0s; r0.y=a0y*i0s; r0.z=a0z*i0s; r0.w=a0w*i0s;
    float4 r1; r1.x=a1x*i1s; r1.y=a1y*i1s; r1.z=a1z*i1s; r1.w=a1w*i1s;
    *(float4*)(ws + vb0) = r0;
    *(float4*)(ws + vb1) = r1;
  } else {
    float a0x=0,a0y=0,a0z=0,a0w=0, a1x=0,a1y=0,a1z=0,a1w=0;
    const float4* x4 = (const float4*)x;
    if (ci == 0){
      size_t base = ((size_t)(b*256 + 2*l) * 64) * 64;
      #pragma unroll 2
      for (int c=0;c<64;++c){
        float4 A  = x4[base + c*64 + lane];
        float4 Bv = x4[base + 4096 + c*64 + lane];
        float mx=(A.x-Bv.x)*IS2f, my=(A.y-Bv.y)*IS2f, mz=(A.z-Bv.z)*IS2f, mw=(A.w-Bv.w)*IS2f;
        float uc0 = uss[0][c], uc1 = uss[1][c];
        a0x += uc0*mx; a0y += uc0*my; a0z += uc0*mz; a0w += uc0*mw;
        a1x += uc1*mx; a1y += uc1*my; a1z += uc1*mz; a1w += uc1*mw;
      }
    } else {
      float sg = (ci==1) ? -0.5f : 0.5f;
      size_t base = ((size_t)(b*256 + 4*l) * 64) * 64;
      #pragma unroll 2
      for (int c=0;c<64;++c){
        float4 A  = x4[base + c*64 + lane];
        float4 B1 = x4[base + 4096 + c*64 + lane];
        float4 C1 = x4[base + 8192 + c*64 + lane];
        float4 D1 = x4[base + 12288 + c*64 + lane];
        float mx=(A.x+B1.x)*0.5f + (C1.x+D1.x)*sg;
        float my=(A.y+B1.y)*0.5f + (C1.y+D1.y)*sg;
        float mz=(A.z+B1.z)*0.5f + (C1.z+D1.z)*sg;
        float mw=(A.w+B1.w)*0.5f + (C1.w+D1.w)*sg;
        float uc0 = uss[0][c], uc1 = uss[1][c];
        a0x += uc0*mx; a0y += uc0*my; a0z += uc0*mz; a0w += uc0*mw;
        a1x += uc1*mx; a1y += uc1*my; a1z += uc1*mz; a1w += uc1*mw;
      }
    }
    ws[vb0+0]=a0x*i0s; ws[vb0+1]=a0y*i0s; ws[vb0+2]=a0z*i0s; ws[vb0+3]=a0w*i0s;
    ws[vb1+0]=a1x*i1s; ws[vb1+1]=a1y*i1s; ws[vb1+2]=a1z*i1s; ws[vb1+3]=a1w*i1s;
  }
}

// ---------------------------------------------------------------------------
// Kernel 3: writer (unchanged).
// ---------------------------------------------------------------------------
__global__ __launch_bounds__(256) void k_out(const float* __restrict__ x,
                                             const float* __restrict__ ws,
                                             float* __restrict__ out){
  __shared__ float d1[128*33];
  __shared__ float d2[64*33];
  __shared__ float a2s[64*33];
  __shared__ float Vs[2*128*33];
  __shared__ float Us[512];

  int nt = blockIdx.x, c = blockIdx.y, b = blockIdx.z;
  int n0 = nt * 32, tid = threadIdx.x;
  float* a1 = Vs;

  const float4* x4 = (const float4*)x;
  #pragma unroll
  for (int e=0;e<4;++e){
    int f = tid + 256*e; int l1 = f>>3, d4 = f&7;
    size_t r = ((size_t)(b*256 + 2*l1)*64 + c)*64 + (n0>>2) + d4;
    float4 A = x4[r], Bv = x4[r + 4096];
    int o = l1*33 + 4*d4;
    d1[o+0]=(A.x-Bv.x)*IS2f; d1[o+1]=(A.y-Bv.y)*IS2f; d1[o+2]=(A.z-Bv.z)*IS2f; d1[o+3]=(A.w-Bv.w)*IS2f;
    a1[o+0]=(A.x+Bv.x)*IS2f; a1[o+1]=(A.y+Bv.y)*IS2f; a1[o+2]=(A.z+Bv.z)*IS2f; a1[o+3]=(A.w+Bv.w)*IS2f;
  }
  __syncthreads();
  #pragma unroll
  for (int e=0;e<2;++e){
    int f = tid + 256*e; int l2 = f>>3, d4 = f&7;
    #pragma unroll
    for (int j=0;j<4;++j){
      int dn = 4*d4 + j;
      float aa = a1[(2*l2)*33 + dn], bb = a1[(2*l2+1)*33 + dn];
      d2[l2*33+dn]  = (aa-bb)*IS2f;
      a2s[l2*33+dn] = (aa+bb)*IS2f;
    }
  }
  #pragma unroll
  for (int e=0;e<2;++e){
    int idx = tid + 256*e;
    int j, l, L, so;
    if (idx < 256)      { j=idx>>7;        l=idx&127; L=128; so=0; }
    else if (idx < 384) { j=(idx-256)>>6;  l=idx&63;  L=64;  so=65536; }
    else                { j=(idx-384)>>6;  l=idx&63;  L=64;  so=98304; }
    Us[idx] = ws[WS_SU + so + ((size_t)(b*2+j)*64 + c)*L + l];
  }
  __syncthreads();

  for (int cc=0; cc<3; ++cc){
    int L   = (cc==0) ? 128 : 64;
    int pad = 256 - L;
    int sb  = cc*3;
    int uo  = (cc==0) ? 0 : (cc==1) ? 256 : 384;
    const float* cf = (cc==0) ? d1 : (cc==1) ? d2 : a2s;

    int iters = (2*L*32) >> 8;
    for (int e=0;e<iters;++e){
      int idx = tid + 256*e;
      int j = (idx >= L*32) ? 1 : 0;
      int rem = idx - j*L*32;
      int ll = rem >> 5, dn = rem & 31;
      Vs[j*4224 + ll*33 + dn] =
        ws[WS_VV + vv_base(cc) + ((size_t)(b*2+j)*L + ll)*256 + n0 + dn];
    }
    __syncthreads();

    int l = tid - pad;
    bool inr = (l >= 0);
    size_t obase = (size_t)sb*16777216 + (size_t)b*4194304 + (size_t)c*65536
                 + (size_t)n0*256 + tid;
    #pragma unroll 4
    for (int dn=0; dn<32; ++dn){
      float v0 = 0.f, v1 = 0.f, rv = 0.f;
      if (inr){
        float q0 = Us[uo + l]     * Vs[l*33 + dn];
        float q1 = Us[uo + L + l] * Vs[4224 + l*33 + dn];
        v0 = q0; v1 = q1;
        rv = cf[l*33 + dn] - q0 - q1;
      }
      out[obase + dn*256]            = v0;
      out[obase + dn*256 + 16777216] = v1;
      out[obase + dn*256 + 33554432] = rv;
    }
    __syncthreads();
  }
}

// ---------------------------------------------------------------------------
extern "C" void kernel_launch(void* const* d_in, const int* in_sizes, int n_in,
                              void* d_out, int out_size, void* d_ws, size_t ws_size,
                              hipStream_t stream) {
  const float* x = (const float*)d_in[0];
  const float* p = (const float*)d_in[1];
  float* out = (float*)d_out;
  float* ws  = (float*)d_ws;

  int useB = (ws_size >= (size_t)(WS_B + 1024ull*8192ull) * 4ull) ? 1 : 0;

  k_fact <<<1024, 256, 0, stream>>>(x, p, ws, useB);
  k_solve<<<1024, 128, 0, stream>>>(x, ws, useB);
  k_out  <<<dim3(8,64,4), 256, 0, stream>>>(x, ws, out);
}